// Round 1
// baseline (138.306 us; speedup 1.0000x reference)
//
#include <hip/hip_runtime.h>
#include <hip/hip_bf16.h>

typedef __attribute__((ext_vector_type(8))) short bf16x8;
typedef __attribute__((ext_vector_type(4))) float f32x4;
typedef __attribute__((ext_vector_type(4))) int i32x4;

#define BSZ   8192
#define DDIM  128
#define NCLS  512
#define NBLK  (BSZ / 128)   // 64
#define MAXN  512           // max members per class supported (actual ~16-40)

__global__ void zero_kernel(int* p, int nwords) {
  int i = blockIdx.x * blockDim.x + threadIdx.x;
  if (i < nwords) p[i] = 0;
}

// Convert score -> bf16 copy, compute exact fp32 row magnitudes.
__global__ void prep_kernel(const float* __restrict__ score,
                            __hip_bfloat16* __restrict__ Sbf,
                            float* __restrict__ mag) {
  int row = blockIdx.x;        // 8192 blocks
  int t = threadIdx.x;         // 128 threads
  float v = score[row * DDIM + t];
  Sbf[row * DDIM + t] = __float2bfloat16(v);
  float sq = v * v;
  #pragma unroll
  for (int m = 1; m < 64; m <<= 1) sq += __shfl_xor(sq, m);
  __shared__ float tmp[2];
  if ((t & 63) == 0) tmp[t >> 6] = sq;
  __syncthreads();
  if (t == 0) mag[row] = tmp[0] + tmp[1];
}

__global__ void hist_kernel(const int* __restrict__ targets, int* counts) {
  int i = blockIdx.x * blockDim.x + threadIdx.x;
  if (i < BSZ) atomicAdd(&counts[targets[i]], 1);
}

__global__ void scan_kernel(const int* __restrict__ counts, int* offsets) {
  if (threadIdx.x == 0) {
    int run = 0;
    for (int c = 0; c < NCLS; ++c) { offsets[c] = run; run += counts[c]; }
  }
}

__global__ void scatter_kernel(const int* __restrict__ targets,
                               const int* __restrict__ offsets,
                               int* cursors, int* list) {
  int i = blockIdx.x * blockDim.x + threadIdx.x;
  if (i < BSZ) {
    int t = targets[i];
    int p = atomicAdd(&cursors[t], 1);
    list[offsets[t] + p] = i;
  }
}

// Dense symmetric pass: for each upper-triangular 128x128 tile, compute
// sim = S*S^T via bf16 MFMA, then e = exp(1 - dist) and accumulate row sums
// (and col sums for off-diagonal tiles, by symmetry) into Nfull.
__launch_bounds__(256)
__global__ void dense_pass(const __hip_bfloat16* __restrict__ Sbf,
                           const float* __restrict__ mag,
                           float* __restrict__ Nfull) {
  int bi = blockIdx.x % NBLK;
  int bj = blockIdx.x / NBLK;
  if (bi > bj) return;                 // symmetry: upper triangle only
  const int i0 = bi * 128, j0 = bj * 128;
  __shared__ char As[128 * 256];       // 128 rows x 128 bf16, XOR-swizzled
  __shared__ char Bs[128 * 256];
  const int tid = threadIdx.x;
  {
    const i32x4* gA = (const i32x4*)(Sbf + (size_t)i0 * DDIM);
    const i32x4* gB = (const i32x4*)(Sbf + (size_t)j0 * DDIM);
    #pragma unroll
    for (int it = 0; it < 8; ++it) {
      int chunk = tid + it * 256;      // 2048 16B chunks per tile
      int row = chunk >> 4;
      int colb = (chunk & 15) << 4;
      int sw = colb ^ ((row & 7) << 4);
      *(i32x4*)(As + row * 256 + sw) = gA[chunk];
      *(i32x4*)(Bs + row * 256 + sw) = gB[chunk];
    }
  }
  __syncthreads();
  const int wid = tid >> 6, l = tid & 63;
  const int wr = wid >> 1, wc = wid & 1;       // 2x2 wave grid, 64x64 each
  const int lr = l >> 4, lc = l & 15;
  f32x4 acc[4][4] = {};
  #pragma unroll
  for (int ks = 0; ks < 4; ++ks) {             // K = 128 in 4 steps of 32
    const int colb = (ks * 32 + lr * 8) * 2;
    bf16x8 af[4], bfr[4];
    #pragma unroll
    for (int m = 0; m < 4; ++m) {
      int row = wr * 64 + m * 16 + lc;
      af[m] = *(const bf16x8*)(As + row * 256 + (colb ^ ((row & 7) << 4)));
    }
    #pragma unroll
    for (int n = 0; n < 4; ++n) {
      int row = wc * 64 + n * 16 + lc;
      bfr[n] = *(const bf16x8*)(Bs + row * 256 + (colb ^ ((row & 7) << 4)));
    }
    #pragma unroll
    for (int m = 0; m < 4; ++m)
      #pragma unroll
      for (int n = 0; n < 4; ++n)
        acc[m][n] = __builtin_amdgcn_mfma_f32_16x16x32_bf16(af[m], bfr[n], acc[m][n], 0, 0, 0);
  }
  // epilogue: e[i][j] = exp(1 - sqrt(relu(mag_i + mag_j - 2 sim)))
  float magj[4], magi[4][4];
  #pragma unroll
  for (int n = 0; n < 4; ++n) magj[n] = mag[j0 + wc * 64 + n * 16 + lc];
  #pragma unroll
  for (int m = 0; m < 4; ++m)
    #pragma unroll
    for (int r = 0; r < 4; ++r)
      magi[m][r] = mag[i0 + wr * 64 + m * 16 + lr * 4 + r];
  float rs[4][4] = {{0.0f}};
  float cs[4] = {0.0f, 0.0f, 0.0f, 0.0f};
  const bool diag = (bi == bj);
  #pragma unroll
  for (int m = 0; m < 4; ++m)
    #pragma unroll
    for (int n = 0; n < 4; ++n)
      #pragma unroll
      for (int r = 0; r < 4; ++r) {
        float s = acc[m][n][r];                    // C layout: col=lane&15, row=(lane>>4)*4+reg
        float d2 = fmaxf(magi[m][r] + magj[n] - 2.0f * s, 0.0f);
        float e = __expf(1.0f - sqrtf(d2));
        if (diag && (wr * 64 + m * 16 + lr * 4 + r) == (wc * 64 + n * 16 + lc))
          e = 0.0f;                                // exclude i == j
        rs[m][r] += e;
        cs[n] += e;
      }
  // row sums -> Nfull[i0 + ...]
  #pragma unroll
  for (int m = 0; m < 4; ++m)
    #pragma unroll
    for (int r = 0; r < 4; ++r) {
      float v = rs[m][r];
      v += __shfl_xor(v, 1); v += __shfl_xor(v, 2);
      v += __shfl_xor(v, 4); v += __shfl_xor(v, 8);
      if (lc == 0) atomicAdd(&Nfull[i0 + wr * 64 + m * 16 + lr * 4 + r], v);
    }
  // col sums -> Nfull[j0 + ...] (symmetric contribution), off-diagonal only
  if (!diag) {
    #pragma unroll
    for (int n = 0; n < 4; ++n) {
      float v = cs[n];
      v += __shfl_xor(v, 16); v += __shfl_xor(v, 32);
      if (lr == 0) atomicAdd(&Nfull[j0 + wc * 64 + n * 16 + lc], v);
    }
  }
}

// Per-class pass: exact fp32 pairwise distances among class members.
// Phase B: N_same[i]; then N = N_full - N_same; Phase C: loss + pair count.
__launch_bounds__(256)
__global__ void class_pass(const float* __restrict__ score,
                           const float* __restrict__ mag,
                           const float* __restrict__ Nfull,
                           const int* __restrict__ counts,
                           const int* __restrict__ offsets,
                           const int* __restrict__ list,
                           float* lossAcc, float* cntAcc) {
  const int c = blockIdx.x;
  int n = counts[c];
  if (n < 2) return;
  if (n > MAXN) n = MAXN;   // defensive; cannot happen for this data
  const int tid = threadIdx.x;
  const int off = offsets[c];
  __shared__ int mem[MAXN];
  __shared__ float Ns[MAXN];
  __shared__ float Nf[MAXN];
  for (int i = tid; i < n; i += 256) { mem[i] = list[off + i]; Ns[i] = 0.0f; }
  __syncthreads();
  const int npairs = n * n;
  for (int p = tid; p < npairs; p += 256) {
    int i = p / n, j = p - i * n;
    if (i == j) continue;
    int gi = mem[i], gj = mem[j];
    const f32x4* ra = (const f32x4*)(score + (size_t)gi * DDIM);
    const f32x4* rb = (const f32x4*)(score + (size_t)gj * DDIM);
    float dot = 0.0f;
    #pragma unroll
    for (int k = 0; k < DDIM / 4; ++k) {
      f32x4 a = ra[k], b = rb[k];
      dot += a[0] * b[0] + a[1] * b[1] + a[2] * b[2] + a[3] * b[3];
    }
    float d2 = fmaxf(mag[gi] + mag[gj] - 2.0f * dot, 0.0f);
    float e = __expf(1.0f - sqrtf(d2));
    atomicAdd(&Ns[i], e);
  }
  __syncthreads();
  for (int i = tid; i < n; i += 256) Nf[i] = Nfull[mem[i]] - Ns[i];
  __syncthreads();
  float lloss = 0.0f, lcnt = 0.0f;
  for (int p = tid; p < npairs; p += 256) {
    int i = p / n, j = p - i * n;
    if (i == j) continue;
    int gi = mem[i], gj = mem[j];
    const f32x4* ra = (const f32x4*)(score + (size_t)gi * DDIM);
    const f32x4* rb = (const f32x4*)(score + (size_t)gj * DDIM);
    float dot = 0.0f;
    #pragma unroll
    for (int k = 0; k < DDIM / 4; ++k) {
      f32x4 a = ra[k], b = rb[k];
      dot += a[0] * b[0] + a[1] * b[1] + a[2] * b[2] + a[3] * b[3];
    }
    float d2 = fmaxf(mag[gi] + mag[gj] - 2.0f * dot, 0.0f);
    float dd = sqrtf(d2);
    float ln = logf(Nf[i] + Nf[j]) + dd;
    if (ln > 0.0f) lloss += ln * ln;
    lcnt += 1.0f;
  }
  #pragma unroll
  for (int m = 1; m < 64; m <<= 1) {
    lloss += __shfl_xor(lloss, m);
    lcnt  += __shfl_xor(lcnt, m);
  }
  __shared__ float redL[4], redC[4];
  if ((tid & 63) == 0) { redL[tid >> 6] = lloss; redC[tid >> 6] = lcnt; }
  __syncthreads();
  if (tid == 0) {
    atomicAdd(lossAcc, redL[0] + redL[1] + redL[2] + redL[3]);
    atomicAdd(cntAcc, redC[0] + redC[1] + redC[2] + redC[3]);
  }
}

__global__ void finalize_kernel(const float* lossAcc, const float* cntAcc,
                                float* out) {
  if (threadIdx.x == 0) out[0] = lossAcc[0] / (4.0f * cntAcc[0]);
}

extern "C" void kernel_launch(void* const* d_in, const int* in_sizes, int n_in,
                              void* d_out, int out_size, void* d_ws, size_t ws_size,
                              hipStream_t stream) {
  const float* score = (const float*)d_in[0];
  const int* targets = (const int*)d_in[1];
  float* out = (float*)d_out;

  char* ws = (char*)d_ws;
  size_t cur = 0;
  auto alloc = [&](size_t bytes) -> void* {
    void* p = ws + cur;
    cur += (bytes + 255) & ~(size_t)255;
    return p;
  };
  __hip_bfloat16* Sbf = (__hip_bfloat16*)alloc((size_t)BSZ * DDIM * 2);
  float* mag = (float*)alloc(BSZ * 4);
  char* zstart = ws + cur;          // everything below is zeroed each call
  float* Nfull  = (float*)alloc(BSZ * 4);
  int* counts   = (int*)alloc(NCLS * 4);
  int* cursors  = (int*)alloc(NCLS * 4);
  float* lossAcc = (float*)alloc(4);
  float* cntAcc  = (float*)alloc(4);
  char* zend = ws + cur;
  int* offsets = (int*)alloc(NCLS * 4);
  int* list    = (int*)alloc(BSZ * 4);
  int zwords = (int)((zend - zstart) / 4);

  zero_kernel<<<(zwords + 255) / 256, 256, 0, stream>>>((int*)zstart, zwords);
  prep_kernel<<<BSZ, DDIM, 0, stream>>>(score, Sbf, mag);
  hist_kernel<<<BSZ / 256, 256, 0, stream>>>(targets, counts);
  scan_kernel<<<1, 64, 0, stream>>>(counts, offsets);
  scatter_kernel<<<BSZ / 256, 256, 0, stream>>>(targets, offsets, cursors, list);
  dense_pass<<<NBLK * NBLK, 256, 0, stream>>>(Sbf, mag, Nfull);
  class_pass<<<NCLS, 256, 0, stream>>>(score, mag, Nfull, counts, offsets, list,
                                       lossAcc, cntAcc);
  finalize_kernel<<<1, 1, 0, stream>>>(lossAcc, cntAcc, out);
}

// Round 2
// 92.935 us; speedup vs baseline: 1.4882x; 1.4882x over previous
//
#include <hip/hip_runtime.h>
#include <hip/hip_bf16.h>

typedef __attribute__((ext_vector_type(8))) short bf16x8;
typedef __attribute__((ext_vector_type(4))) float f32x4;
typedef __attribute__((ext_vector_type(4))) int i32x4;

#define BSZ   8192
#define DDIM  128
#define NCLS  512
#define SLOT  64              // max members/class supported (actual max ~35)
#define NB    128             // number of 64-row panels
#define NTRI  (NB * (NB + 1) / 2)   // 8256 upper-triangular 64x64 tiles

#define L2E 1.44269504088896340736f
#define RLN2 0.69314718055994530942f

__device__ __forceinline__ float fast_sqrt(float x) {
  float r; asm("v_sqrt_f32 %0, %1" : "=v"(r) : "v"(x)); return r;
}
__device__ __forceinline__ float fast_exp2(float x) {
  float r; asm("v_exp_f32 %0, %1" : "=v"(r) : "v"(x)); return r;
}
__device__ __forceinline__ float fast_log2(float x) {
  float r; asm("v_log_f32 %0, %1" : "=v"(r) : "v"(x)); return r;
}

__global__ void zero_kernel(int* p, int nwords) {
  int i = blockIdx.x * blockDim.x + threadIdx.x;
  if (i < nwords) p[i] = 0;
}

// score -> bf16 copy + exact fp32 row magnitudes. 16 lanes per row, 8 elems/lane.
__global__ void prep_kernel(const float* __restrict__ score,
                            __hip_bfloat16* __restrict__ Sbf,
                            float* __restrict__ mag) {
  int gid = blockIdx.x * 256 + threadIdx.x;   // 131072 threads
  int row = gid >> 4, sub = gid & 15;
  const f32x4* src = (const f32x4*)(score + (size_t)row * DDIM + sub * 8);
  f32x4 a = src[0], b = src[1];
  union { ushort u[8]; i32x4 v; } pk;
  #pragma unroll
  for (int k = 0; k < 4; ++k) {
    __hip_bfloat16 ha = __float2bfloat16(a[k]);
    __hip_bfloat16 hb = __float2bfloat16(b[k]);
    pk.u[k] = *(const ushort*)&ha;
    pk.u[4 + k] = *(const ushort*)&hb;
  }
  *(i32x4*)((short*)Sbf + (size_t)row * DDIM + sub * 8) = pk.v;
  float sq = a[0]*a[0] + a[1]*a[1] + a[2]*a[2] + a[3]*a[3]
           + b[0]*b[0] + b[1]*b[1] + b[2]*b[2] + b[3]*b[3];
  sq += __shfl_xor(sq, 1); sq += __shfl_xor(sq, 2);
  sq += __shfl_xor(sq, 4); sq += __shfl_xor(sq, 8);
  if (sub == 0) mag[row] = sq;
}

// Bucket sample indices by class: counts[] doubles as cursor.
__global__ void scatter_kernel(const int* __restrict__ targets,
                               int* counts, int* list) {
  int i = blockIdx.x * 256 + threadIdx.x;
  if (i < BSZ) {
    int t = targets[i];
    int p = atomicAdd(&counts[t], 1);
    if (p < SLOT) list[t * SLOT + p] = i;
  }
}

// Dense symmetric pass: one wave per upper-triangular 64x64 tile.
// No LDS: fragments loaded directly from L2-resident bf16 matrix.
__launch_bounds__(64, 4)
__global__ void dense_pass(const __hip_bfloat16* __restrict__ Sbf,
                           const float* __restrict__ mag,
                           float* __restrict__ Nfull) {
  const int t = blockIdx.x;
  int bj = (int)((sqrtf(8.0f * (float)t + 1.0f) - 1.0f) * 0.5f);
  while ((bj + 1) * (bj + 2) / 2 <= t) ++bj;
  while (bj * (bj + 1) / 2 > t) --bj;
  const int bi = t - bj * (bj + 1) / 2;          // bi <= bj
  const int i0 = bi * 64, j0 = bj * 64;

  const int l = threadIdx.x, lr = l >> 4, lc = l & 15;
  const short* SA = (const short*)Sbf + (size_t)(i0 + lc) * DDIM + lr * 8;
  const short* SB = (const short*)Sbf + (size_t)(j0 + lc) * DDIM + lr * 8;

  f32x4 acc[4][4] = {};
  #pragma unroll
  for (int ks = 0; ks < 4; ++ks) {               // K = 128 in 4 steps of 32
    bf16x8 af[4], bfr[4];
    #pragma unroll
    for (int m = 0; m < 4; ++m)
      af[m] = *(const bf16x8*)(SA + m * 16 * DDIM + ks * 32);
    #pragma unroll
    for (int n = 0; n < 4; ++n)
      bfr[n] = *(const bf16x8*)(SB + n * 16 * DDIM + ks * 32);
    #pragma unroll
    for (int m = 0; m < 4; ++m)
      #pragma unroll
      for (int n = 0; n < 4; ++n)
        acc[m][n] = __builtin_amdgcn_mfma_f32_16x16x32_bf16(af[m], bfr[n], acc[m][n], 0, 0, 0);
  }

  float magj[4], magi[4][4];
  #pragma unroll
  for (int n = 0; n < 4; ++n) magj[n] = mag[j0 + n * 16 + lc];
  #pragma unroll
  for (int m = 0; m < 4; ++m)
    #pragma unroll
    for (int r = 0; r < 4; ++r)
      magi[m][r] = mag[i0 + m * 16 + lr * 4 + r];

  float rs[4][4] = {};
  float cs[4] = {};
  const bool diag = (bi == bj);
  #pragma unroll
  for (int m = 0; m < 4; ++m)
    #pragma unroll
    for (int n = 0; n < 4; ++n)
      #pragma unroll
      for (int r = 0; r < 4; ++r) {
        // C layout: col = lane&15, row = (lane>>4)*4 + reg
        float d2 = fmaxf(magi[m][r] + magj[n] - 2.0f * acc[m][n][r], 0.0f);
        float e = fast_exp2((1.0f - fast_sqrt(d2)) * L2E);
        if (diag && (m * 16 + lr * 4 + r) == (n * 16 + lc)) e = 0.0f;
        rs[m][r] += e;
        cs[n] += e;
      }
  // row sums -> Nfull[i0 + ...]
  #pragma unroll
  for (int m = 0; m < 4; ++m)
    #pragma unroll
    for (int r = 0; r < 4; ++r) {
      float v = rs[m][r];
      v += __shfl_xor(v, 1); v += __shfl_xor(v, 2);
      v += __shfl_xor(v, 4); v += __shfl_xor(v, 8);
      if (lc == 0) atomicAdd(&Nfull[i0 + m * 16 + lr * 4 + r], v);
    }
  // col sums -> Nfull[j0 + ...] (symmetric contribution), off-diagonal only
  if (!diag) {
    #pragma unroll
    for (int n = 0; n < 4; ++n) {
      float v = cs[n];
      v += __shfl_xor(v, 16); v += __shfl_xor(v, 32);
      if (lr == 0) atomicAdd(&Nfull[j0 + n * 16 + lc], v);
    }
  }
}

// Per-class pass: exact fp32 pairwise distances among class members.
__launch_bounds__(256)
__global__ void class_pass(const float* __restrict__ score,
                           const float* __restrict__ mag,
                           const float* __restrict__ Nfull,
                           const int* __restrict__ counts,
                           const int* __restrict__ list,
                           float* lossAcc, float* cntAcc) {
  const int c = blockIdx.x;
  int n = counts[c];
  if (n < 2) return;
  if (n > SLOT) n = SLOT;   // defensive; cannot happen for this data
  const int tid = threadIdx.x;
  __shared__ int mem[SLOT];
  __shared__ float Ns[SLOT];
  __shared__ float Nf[SLOT];
  __shared__ float dmat[SLOT * SLOT];   // 16 KB: cached distances
  for (int i = tid; i < n; i += 256) { mem[i] = list[c * SLOT + i]; Ns[i] = 0.0f; }
  __syncthreads();
  const int np = n * n;
  for (int p = tid; p < np; p += 256) {
    int i = p / n, j = p - i * n;
    float dd = 0.0f;
    if (i != j) {
      int gi = mem[i], gj = mem[j];
      const f32x4* ra = (const f32x4*)(score + (size_t)gi * DDIM);
      const f32x4* rb = (const f32x4*)(score + (size_t)gj * DDIM);
      float dot = 0.0f;
      #pragma unroll
      for (int k = 0; k < DDIM / 4; ++k) {
        f32x4 a = ra[k], b = rb[k];
        dot += a[0]*b[0] + a[1]*b[1] + a[2]*b[2] + a[3]*b[3];
      }
      float d2 = fmaxf(mag[gi] + mag[gj] - 2.0f * dot, 0.0f);
      dd = fast_sqrt(d2);
      atomicAdd(&Ns[i], fast_exp2((1.0f - dd) * L2E));
    }
    dmat[p] = dd;
  }
  __syncthreads();
  for (int i = tid; i < n; i += 256) Nf[i] = Nfull[mem[i]] - Ns[i];
  __syncthreads();
  float lloss = 0.0f, lcnt = 0.0f;
  for (int p = tid; p < np; p += 256) {
    int i = p / n, j = p - i * n;
    if (i == j) continue;
    float ln = fast_log2(Nf[i] + Nf[j]) * RLN2 + dmat[p];
    if (ln > 0.0f) lloss += ln * ln;
    lcnt += 1.0f;
  }
  #pragma unroll
  for (int m = 1; m < 64; m <<= 1) {
    lloss += __shfl_xor(lloss, m);
    lcnt  += __shfl_xor(lcnt, m);
  }
  __shared__ float redL[4], redC[4];
  if ((tid & 63) == 0) { redL[tid >> 6] = lloss; redC[tid >> 6] = lcnt; }
  __syncthreads();
  if (tid == 0) {
    atomicAdd(lossAcc, redL[0] + redL[1] + redL[2] + redL[3]);
    atomicAdd(cntAcc, redC[0] + redC[1] + redC[2] + redC[3]);
  }
}

__global__ void finalize_kernel(const float* lossAcc, const float* cntAcc,
                                float* out) {
  if (threadIdx.x == 0) out[0] = lossAcc[0] / (4.0f * cntAcc[0]);
}

extern "C" void kernel_launch(void* const* d_in, const int* in_sizes, int n_in,
                              void* d_out, int out_size, void* d_ws, size_t ws_size,
                              hipStream_t stream) {
  const float* score = (const float*)d_in[0];
  const int* targets = (const int*)d_in[1];
  float* out = (float*)d_out;

  char* ws = (char*)d_ws;
  size_t cur = 0;
  auto alloc = [&](size_t bytes) -> void* {
    void* p = ws + cur;
    cur += (bytes + 255) & ~(size_t)255;
    return p;
  };
  __hip_bfloat16* Sbf = (__hip_bfloat16*)alloc((size_t)BSZ * DDIM * 2);
  char* zstart = ws + cur;          // everything below is zeroed each call
  float* Nfull   = (float*)alloc(BSZ * 4);
  int*   counts  = (int*)alloc(NCLS * 4);
  float* lossAcc = (float*)alloc(4);
  float* cntAcc  = (float*)alloc(4);
  char* zend = ws + cur;
  float* mag  = (float*)alloc(BSZ * 4);
  int*   list = (int*)alloc(NCLS * SLOT * 4);
  int zwords = (int)((zend - zstart) / 4);

  zero_kernel<<<(zwords + 255) / 256, 256, 0, stream>>>((int*)zstart, zwords);
  prep_kernel<<<BSZ * 16 / 256, 256, 0, stream>>>(score, Sbf, mag);
  scatter_kernel<<<BSZ / 256, 256, 0, stream>>>(targets, counts, list);
  dense_pass<<<NTRI, 64, 0, stream>>>(Sbf, mag, Nfull);
  class_pass<<<NCLS, 256, 0, stream>>>(score, mag, Nfull, counts, list,
                                       lossAcc, cntAcc);
  finalize_kernel<<<1, 1, 0, stream>>>(lossAcc, cntAcc, out);
}

// Round 3
// 88.780 us; speedup vs baseline: 1.5579x; 1.0468x over previous
//
#include <hip/hip_runtime.h>
#include <hip/hip_bf16.h>

typedef __attribute__((ext_vector_type(8))) short bf16x8;
typedef __attribute__((ext_vector_type(4))) float f32x4;
typedef __attribute__((ext_vector_type(4))) int i32x4;

#define BSZ   8192
#define DDIM  128
#define NCLS  512
#define SLOT  64                    // max members/class supported (actual max ~35)
#define NPAN  64                    // 128-row panels
#define NTRI  (NPAN * (NPAN + 1) / 2)   // 2080 upper-triangular 128x128 tiles

#define L2E  1.44269504088896340736f
#define RLN2 0.69314718055994530942f

__device__ __forceinline__ float fast_sqrt(float x) {
  float r; asm("v_sqrt_f32 %0, %1" : "=v"(r) : "v"(x)); return r;
}
__device__ __forceinline__ float fast_exp2(float x) {
  float r; asm("v_exp_f32 %0, %1" : "=v"(r) : "v"(x)); return r;
}
__device__ __forceinline__ float fast_log2(float x) {
  float r; asm("v_log_f32 %0, %1" : "=v"(r) : "v"(x)); return r;
}

// score -> bf16 copy + exact fp32 row magnitudes; block 0 zeroes ctrl words.
__global__ void prep_kernel(const float* __restrict__ score,
                            __hip_bfloat16* __restrict__ Sbf,
                            float* __restrict__ mag,
                            int* __restrict__ ctrl, int ctrlWords) {
  const int tid = threadIdx.x;
  if (blockIdx.x == 0)
    for (int w = tid; w < ctrlWords; w += 256) ctrl[w] = 0;
  int gid = blockIdx.x * 256 + tid;          // 131072 threads
  int row = gid >> 4, sub = gid & 15;
  const f32x4* src = (const f32x4*)(score + (size_t)row * DDIM + sub * 8);
  f32x4 a = src[0], b = src[1];
  union { ushort u[8]; i32x4 v; } pk;
  #pragma unroll
  for (int k = 0; k < 4; ++k) {
    __hip_bfloat16 ha = __float2bfloat16(a[k]);
    __hip_bfloat16 hb = __float2bfloat16(b[k]);
    pk.u[k] = *(const ushort*)&ha;
    pk.u[4 + k] = *(const ushort*)&hb;
  }
  *(i32x4*)((short*)Sbf + (size_t)row * DDIM + sub * 8) = pk.v;
  float sq = a[0]*a[0] + a[1]*a[1] + a[2]*a[2] + a[3]*a[3]
           + b[0]*b[0] + b[1]*b[1] + b[2]*b[2] + b[3]*b[3];
  sq += __shfl_xor(sq, 1); sq += __shfl_xor(sq, 2);
  sq += __shfl_xor(sq, 4); sq += __shfl_xor(sq, 8);
  if (sub == 0) mag[row] = sq;
}

// Bucket sample indices by class: counts[] doubles as cursor.
__global__ void scatter_kernel(const int* __restrict__ targets,
                               int* counts, int* list) {
  int i = blockIdx.x * 256 + threadIdx.x;
  if (i < BSZ) {
    int t = targets[i];
    int p = atomicAdd(&counts[t], 1);
    if (p < SLOT) list[t * SLOT + p] = i;
  }
}

// Dense symmetric pass: one 256-thread block per upper-triangular 128x128
// tile; 2x2 waves of 64x64. No global atomics: per-tile partial row sums
// (slots 0..127) and col sums (128..255, off-diag only) stored to P[t][.].
__launch_bounds__(256, 4)
__global__ void dense_pass(const __hip_bfloat16* __restrict__ Sbf,
                           const float* __restrict__ mag,
                           float* __restrict__ P) {
  const int t = blockIdx.x;
  int bj = (int)((sqrtf(8.0f * (float)t + 1.0f) - 1.0f) * 0.5f);
  while ((bj + 1) * (bj + 2) / 2 <= t) ++bj;
  while (bj * (bj + 1) / 2 > t) --bj;
  const int bi = t - bj * (bj + 1) / 2;          // bi <= bj
  const int i0 = bi * 128, j0 = bj * 128;
  const bool diag = (bi == bj);

  const int tid = threadIdx.x;
  const int wid = tid >> 6, l = tid & 63;
  const int wr = wid >> 1, wc = wid & 1;         // 2x2 wave grid
  const int lr = l >> 4, lc = l & 15;

  const short* SA = (const short*)Sbf + (size_t)(i0 + wr * 64 + lc) * DDIM + lr * 8;
  const short* SB = (const short*)Sbf + (size_t)(j0 + wc * 64 + lc) * DDIM + lr * 8;

  f32x4 acc[4][4] = {};
  #pragma unroll
  for (int ks = 0; ks < 4; ++ks) {               // K = 128 in 4 steps of 32
    bf16x8 af[4], bfr[4];
    #pragma unroll
    for (int m = 0; m < 4; ++m)
      af[m] = *(const bf16x8*)(SA + m * 16 * DDIM + ks * 32);
    #pragma unroll
    for (int n = 0; n < 4; ++n)
      bfr[n] = *(const bf16x8*)(SB + n * 16 * DDIM + ks * 32);
    #pragma unroll
    for (int m = 0; m < 4; ++m)
      #pragma unroll
      for (int n = 0; n < 4; ++n)
        acc[m][n] = __builtin_amdgcn_mfma_f32_16x16x32_bf16(af[m], bfr[n], acc[m][n], 0, 0, 0);
  }

  float magj[4], magi[4][4];
  #pragma unroll
  for (int n = 0; n < 4; ++n) magj[n] = mag[j0 + wc * 64 + n * 16 + lc];
  #pragma unroll
  for (int m = 0; m < 4; ++m)
    #pragma unroll
    for (int r = 0; r < 4; ++r)
      magi[m][r] = mag[i0 + wr * 64 + m * 16 + lr * 4 + r];

  float rs[4][4] = {};
  float cs[4] = {};
  #pragma unroll
  for (int m = 0; m < 4; ++m)
    #pragma unroll
    for (int n = 0; n < 4; ++n)
      #pragma unroll
      for (int r = 0; r < 4; ++r) {
        // C layout: col = lane&15, row = (lane>>4)*4 + reg
        float d2 = fmaxf(magi[m][r] + magj[n] - 2.0f * acc[m][n][r], 0.0f);
        float e = fast_exp2((1.0f - fast_sqrt(d2)) * L2E);
        rs[m][r] += e;
        cs[n] += e;
      }
  // remove self terms (diag tiles, diag waves only; static indexing)
  if (diag && wr == wc) {
    #pragma unroll
    for (int m = 0; m < 4; ++m)
      #pragma unroll
      for (int r = 0; r < 4; ++r) {
        if (lc == lr * 4 + r) {
          float d2 = fmaxf(magi[m][r] + magj[m] - 2.0f * acc[m][m][r], 0.0f);
          rs[m][r] -= fast_exp2((1.0f - fast_sqrt(d2)) * L2E);
        }
      }
  }

  __shared__ float Lrow[128][2];
  __shared__ float Lcol[128][2];
  #pragma unroll
  for (int m = 0; m < 4; ++m)
    #pragma unroll
    for (int r = 0; r < 4; ++r) {
      float v = rs[m][r];
      v += __shfl_xor(v, 1); v += __shfl_xor(v, 2);
      v += __shfl_xor(v, 4); v += __shfl_xor(v, 8);
      if (lc == 0) Lrow[wr * 64 + m * 16 + lr * 4 + r][wc] = v;
    }
  if (!diag) {
    #pragma unroll
    for (int n = 0; n < 4; ++n) {
      float v = cs[n];
      v += __shfl_xor(v, 16); v += __shfl_xor(v, 32);
      if (lr == 0) Lcol[wc * 64 + n * 16 + lc][wr] = v;
    }
  }
  __syncthreads();
  float* Pt = P + (size_t)t * 256;
  if (tid < 128) Pt[tid] = Lrow[tid][0] + Lrow[tid][1];
  else if (!diag) Pt[tid] = Lcol[tid - 128][0] + Lcol[tid - 128][1];
}

// Per-class pass: gather Nfull from tile partials, exact fp32 pairwise
// distances among class members (LDS-staged rows), loss + count; the last
// block to finish finalizes the output (fence + ticket).
__launch_bounds__(256)
__global__ void class_pass(const float* __restrict__ score,
                           const float* __restrict__ mag,
                           const float* __restrict__ P,
                           const int* __restrict__ counts,
                           const int* __restrict__ list,
                           float* lossAcc, float* cntAcc, int* ticket,
                           float* out, int nblocks) {
  const int c = blockIdx.x;
  const int tid = threadIdx.x;
  int n = counts[c];
  if (n > SLOT) n = SLOT;   // defensive; cannot happen for this data
  if (n >= 2) {
    __shared__ float rows[SLOT][132];   // [.][128] holds mag
    __shared__ float Nf[SLOT];
    __shared__ float Ns[SLOT];
    __shared__ int mem[SLOT];
    __shared__ float dmat[SLOT * SLOT];
    __shared__ float redL[4], redC[4];
    for (int i = tid; i < n; i += 256) {
      mem[i] = list[c * SLOT + i];
      Ns[i] = 0.0f; Nf[i] = 0.0f;
    }
    __syncthreads();
    for (int w = tid; w < n * 32; w += 256) {
      int i = w >> 5, ch = w & 31;
      *(f32x4*)&rows[i][ch * 4] = *(const f32x4*)(score + (size_t)mem[i] * DDIM + ch * 4);
    }
    for (int i = tid; i < n; i += 256) rows[i][128] = mag[mem[i]];
    // gather Nfull from the 64 panel partials per member
    for (int w = tid; w < n * 64; w += 256) {
      int i = w >> 6, q = w & 63;
      int gi = mem[i], pp = gi >> 7, off = gi & 127;
      float v = (q >= pp) ? P[(size_t)(q * (q + 1) / 2 + pp) * 256 + off]
                          : P[(size_t)(pp * (pp + 1) / 2 + q) * 256 + 128 + off];
      atomicAdd(&Nf[i], v);
    }
    __syncthreads();
    const int np = n * n;
    for (int p = tid; p < np; p += 256) {
      int i = p / n, j = p - i * n;
      float dd = 0.0f;
      if (i != j) {
        float dot = 0.0f;
        #pragma unroll
        for (int k = 0; k < 32; ++k) {
          f32x4 a = *(const f32x4*)&rows[i][k * 4];
          f32x4 b = *(const f32x4*)&rows[j][k * 4];
          dot += a[0]*b[0] + a[1]*b[1] + a[2]*b[2] + a[3]*b[3];
        }
        float d2 = fmaxf(rows[i][128] + rows[j][128] - 2.0f * dot, 0.0f);
        dd = fast_sqrt(d2);
        atomicAdd(&Ns[i], fast_exp2((1.0f - dd) * L2E));
      }
      dmat[p] = dd;
    }
    __syncthreads();
    for (int i = tid; i < n; i += 256) Nf[i] -= Ns[i];
    __syncthreads();
    float ll = 0.0f, lcn = 0.0f;
    for (int p = tid; p < np; p += 256) {
      int i = p / n, j = p - i * n;
      if (i == j) continue;
      float ln = fast_log2(Nf[i] + Nf[j]) * RLN2 + dmat[p];
      if (ln > 0.0f) ll += ln * ln;
      lcn += 1.0f;
    }
    #pragma unroll
    for (int m = 1; m < 64; m <<= 1) {
      ll  += __shfl_xor(ll, m);
      lcn += __shfl_xor(lcn, m);
    }
    if ((tid & 63) == 0) { redL[tid >> 6] = ll; redC[tid >> 6] = lcn; }
    __syncthreads();
    if (tid == 0) {
      atomicAdd(lossAcc, redL[0] + redL[1] + redL[2] + redL[3]);
      atomicAdd(cntAcc, redC[0] + redC[1] + redC[2] + redC[3]);
    }
  }
  if (tid == 0) {
    __threadfence();
    int done = atomicAdd(ticket, 1);
    if (done == nblocks - 1) {
      float L = atomicAdd(lossAcc, 0.0f);
      float C = atomicAdd(cntAcc, 0.0f);
      out[0] = L / (4.0f * C);
    }
  }
}

extern "C" void kernel_launch(void* const* d_in, const int* in_sizes, int n_in,
                              void* d_out, int out_size, void* d_ws, size_t ws_size,
                              hipStream_t stream) {
  const float* score = (const float*)d_in[0];
  const int* targets = (const int*)d_in[1];
  float* out = (float*)d_out;

  char* ws = (char*)d_ws;
  size_t cur = 0;
  auto alloc = [&](size_t bytes) -> void* {
    void* p = ws + cur;
    cur += (bytes + 255) & ~(size_t)255;
    return p;
  };
  __hip_bfloat16* Sbf = (__hip_bfloat16*)alloc((size_t)BSZ * DDIM * 2);
  float* mag  = (float*)alloc(BSZ * 4);
  int*   ctrl = (int*)alloc(544 * 4);   // counts[512] | loss | cnt | ticket
  int*   list = (int*)alloc(NCLS * SLOT * 4);
  float* P    = (float*)alloc((size_t)NTRI * 256 * 4);

  int*   counts  = ctrl;
  float* lossAcc = (float*)(ctrl + 512);
  float* cntAcc  = (float*)(ctrl + 513);
  int*   ticket  = ctrl + 514;
  const int ctrlWords = 516;

  prep_kernel<<<BSZ * 16 / 256, 256, 0, stream>>>(score, Sbf, mag, ctrl, ctrlWords);
  scatter_kernel<<<BSZ / 256, 256, 0, stream>>>(targets, counts, list);
  dense_pass<<<NTRI, 256, 0, stream>>>(Sbf, mag, P);
  class_pass<<<NCLS, 256, 0, stream>>>(score, mag, P, counts, list,
                                       lossAcc, cntAcc, ticket, out, NCLS);
}

// Round 4
// 78.206 us; speedup vs baseline: 1.7685x; 1.1352x over previous
//
#include <hip/hip_runtime.h>
#include <hip/hip_bf16.h>

typedef __attribute__((ext_vector_type(8))) short bf16x8;
typedef __attribute__((ext_vector_type(4))) float f32x4;
typedef __attribute__((ext_vector_type(4))) int i32x4;

#define BSZ   8192
#define DDIM  128
#define NCLS  512
#define SLOT  64                    // max members/class supported (actual max ~35)
#define NPAN  64                    // 128-row panels
#define NTRI  (NPAN * (NPAN + 1) / 2)   // 2080 upper-triangular 128x128 tiles

#define L2E  1.44269504088896340736f
#define RLN2 0.69314718055994530942f

__device__ __forceinline__ float fast_sqrt(float x) {
  float r; asm("v_sqrt_f32 %0, %1" : "=v"(r) : "v"(x)); return r;
}
__device__ __forceinline__ float fast_exp2(float x) {
  float r; asm("v_exp_f32 %0, %1" : "=v"(r) : "v"(x)); return r;
}
__device__ __forceinline__ float fast_log2(float x) {
  float r; asm("v_log_f32 %0, %1" : "=v"(r) : "v"(x)); return r;
}

// score -> bf16 copy + exact fp32 row magnitudes + class-bucket scatter.
// counts[] must be zeroed before this kernel (hipMemsetAsync in launch).
__global__ void prep_kernel(const float* __restrict__ score,
                            const int* __restrict__ targets,
                            __hip_bfloat16* __restrict__ Sbf,
                            float* __restrict__ mag,
                            int* __restrict__ counts,
                            int* __restrict__ list) {
  int gid = blockIdx.x * 256 + threadIdx.x;   // 131072 threads
  int row = gid >> 4, sub = gid & 15;
  const f32x4* src = (const f32x4*)(score + (size_t)row * DDIM + sub * 8);
  f32x4 a = src[0], b = src[1];
  union { ushort u[8]; i32x4 v; } pk;
  #pragma unroll
  for (int k = 0; k < 4; ++k) {
    __hip_bfloat16 ha = __float2bfloat16(a[k]);
    __hip_bfloat16 hb = __float2bfloat16(b[k]);
    pk.u[k] = *(const ushort*)&ha;
    pk.u[4 + k] = *(const ushort*)&hb;
  }
  *(i32x4*)((short*)Sbf + (size_t)row * DDIM + sub * 8) = pk.v;
  float sq = a[0]*a[0] + a[1]*a[1] + a[2]*a[2] + a[3]*a[3]
           + b[0]*b[0] + b[1]*b[1] + b[2]*b[2] + b[3]*b[3];
  sq += __shfl_xor(sq, 1); sq += __shfl_xor(sq, 2);
  sq += __shfl_xor(sq, 4); sq += __shfl_xor(sq, 8);
  if (sub == 0) {
    mag[row] = sq;
    int t = targets[row];
    int p = atomicAdd(&counts[t], 1);
    if (p < SLOT) list[t * SLOT + p] = row;
  }
}

// Dense symmetric pass: one 256-thread block per upper-triangular 128x128
// tile; 2x2 waves of 64x64. A/B staged to LDS via global_load_lds (16B,
// wave-uniform dest) with XOR-swizzle applied on the global SOURCE address
// (rule #21) and the same involution on ds_read -> conflict-free b128 reads.
// Partial row sums (slots 0..127) / col sums (128..255) stored to P[t][.].
__launch_bounds__(256, 2)
__global__ void dense_pass(const __hip_bfloat16* __restrict__ Sbf,
                           const float* __restrict__ mag,
                           float* __restrict__ P) {
  const int t = blockIdx.x;
  int bj = (int)((sqrtf(8.0f * (float)t + 1.0f) - 1.0f) * 0.5f);
  while ((bj + 1) * (bj + 2) / 2 <= t) ++bj;
  while (bj * (bj + 1) / 2 > t) --bj;
  const int bi = t - bj * (bj + 1) / 2;          // bi <= bj
  const int i0 = bi * 128, j0 = bj * 128;
  const bool diag = (bi == bj);

  __shared__ char As[128 * 256];                 // 32 KB, swizzled layout
  __shared__ char Bs[128 * 256];
  __shared__ float Lrow[128][2];
  __shared__ float Lcol[128][2];

  const int tid = threadIdx.x;
  const int wid = tid >> 6, l = tid & 63;
  const int wr = wid >> 1, wc = wid & 1;         // 2x2 wave grid
  const int lr = l >> 4, lc = l & 15;
  const short* S = (const short*)Sbf;

  // Stage: physical chunk p (16B) holds global chunk (p&15)^((p>>4)&7).
  #pragma unroll
  for (int it = 0; it < 8; ++it) {
    int p = tid + it * 256;                      // 2048 chunks per tile
    int r = p >> 4;
    int g = (p & 15) ^ (r & 7);
    const void* gsrcA = (const void*)(S + (size_t)(i0 + r) * DDIM + g * 8);
    void* ldstA = (void*)(As + (wid * 64 + it * 256) * 16);
    __builtin_amdgcn_global_load_lds(
        (const __attribute__((address_space(1))) void*)gsrcA,
        (__attribute__((address_space(3))) void*)ldstA, 16, 0, 0);
    if (!diag) {
      const void* gsrcB = (const void*)(S + (size_t)(j0 + r) * DDIM + g * 8);
      void* ldstB = (void*)(Bs + (wid * 64 + it * 256) * 16);
      __builtin_amdgcn_global_load_lds(
          (const __attribute__((address_space(1))) void*)gsrcB,
          (__attribute__((address_space(3))) void*)ldstB, 16, 0, 0);
    }
  }

  // Prefetch mags while stage is in flight.
  float magj[4], magi[4][4];
  #pragma unroll
  for (int n = 0; n < 4; ++n) magj[n] = mag[j0 + wc * 64 + n * 16 + lc];
  #pragma unroll
  for (int m = 0; m < 4; ++m)
    #pragma unroll
    for (int r = 0; r < 4; ++r)
      magi[m][r] = mag[i0 + wr * 64 + m * 16 + lr * 4 + r];

  __syncthreads();

  const char* BB = diag ? As : Bs;
  f32x4 acc[4][4] = {};
  #pragma unroll
  for (int ks = 0; ks < 4; ++ks) {               // K = 128 in 4 steps of 32
    bf16x8 af[4], bfr[4];
    #pragma unroll
    for (int m = 0; m < 4; ++m) {
      int r = wr * 64 + m * 16 + lc;
      int c = ks * 4 + lr;
      af[m] = *(const bf16x8*)(As + r * 256 + ((c ^ (r & 7)) << 4));
    }
    #pragma unroll
    for (int n = 0; n < 4; ++n) {
      int r = wc * 64 + n * 16 + lc;
      int c = ks * 4 + lr;
      bfr[n] = *(const bf16x8*)(BB + r * 256 + ((c ^ (r & 7)) << 4));
    }
    #pragma unroll
    for (int m = 0; m < 4; ++m)
      #pragma unroll
      for (int n = 0; n < 4; ++n)
        acc[m][n] = __builtin_amdgcn_mfma_f32_16x16x32_bf16(af[m], bfr[n], acc[m][n], 0, 0, 0);
  }

  float rs[4][4] = {};
  float cs[4] = {};
  #pragma unroll
  for (int m = 0; m < 4; ++m)
    #pragma unroll
    for (int n = 0; n < 4; ++n)
      #pragma unroll
      for (int r = 0; r < 4; ++r) {
        // C layout: col = lane&15, row = (lane>>4)*4 + reg
        float d2 = fmaxf(magi[m][r] + magj[n] - 2.0f * acc[m][n][r], 0.0f);
        float e = fast_exp2((1.0f - fast_sqrt(d2)) * L2E);
        rs[m][r] += e;
        cs[n] += e;
      }
  // remove self terms (diag tiles, diag waves only; static indexing)
  if (diag && wr == wc) {
    #pragma unroll
    for (int m = 0; m < 4; ++m)
      #pragma unroll
      for (int r = 0; r < 4; ++r) {
        if (lc == lr * 4 + r) {
          float d2 = fmaxf(magi[m][r] + magj[m] - 2.0f * acc[m][m][r], 0.0f);
          rs[m][r] -= fast_exp2((1.0f - fast_sqrt(d2)) * L2E);
        }
      }
  }

  #pragma unroll
  for (int m = 0; m < 4; ++m)
    #pragma unroll
    for (int r = 0; r < 4; ++r) {
      float v = rs[m][r];
      v += __shfl_xor(v, 1); v += __shfl_xor(v, 2);
      v += __shfl_xor(v, 4); v += __shfl_xor(v, 8);
      if (lc == 0) Lrow[wr * 64 + m * 16 + lr * 4 + r][wc] = v;
    }
  if (!diag) {
    #pragma unroll
    for (int n = 0; n < 4; ++n) {
      float v = cs[n];
      v += __shfl_xor(v, 16); v += __shfl_xor(v, 32);
      if (lr == 0) Lcol[wc * 64 + n * 16 + lc][wr] = v;
    }
  }
  __syncthreads();
  float* Pt = P + (size_t)t * 256;
  if (tid < 128) Pt[tid] = Lrow[tid][0] + Lrow[tid][1];
  else if (!diag) Pt[tid] = Lcol[tid - 128][0] + Lcol[tid - 128][1];
}

// Per-class pass: gather Nfull from tile partials, exact fp32 pairwise
// distances among class members (LDS-staged rows), loss + count; the last
// block to finish finalizes the output (fence + ticket).
__launch_bounds__(256)
__global__ void class_pass(const float* __restrict__ score,
                           const float* __restrict__ mag,
                           const float* __restrict__ P,
                           const int* __restrict__ counts,
                           const int* __restrict__ list,
                           float* lossAcc, float* cntAcc, int* ticket,
                           float* out, int nblocks) {
  const int c = blockIdx.x;
  const int tid = threadIdx.x;
  int n = counts[c];
  if (n > SLOT) n = SLOT;   // defensive; cannot happen for this data
  if (n >= 2) {
    __shared__ float rows[SLOT][132];   // [.][128] holds mag
    __shared__ float Nf[SLOT];
    __shared__ float Ns[SLOT];
    __shared__ int mem[SLOT];
    __shared__ float dmat[SLOT * SLOT];
    __shared__ float redL[4], redC[4];
    for (int i = tid; i < n; i += 256) {
      mem[i] = list[c * SLOT + i];
      Ns[i] = 0.0f; Nf[i] = 0.0f;
    }
    __syncthreads();
    for (int w = tid; w < n * 32; w += 256) {
      int i = w >> 5, ch = w & 31;
      *(f32x4*)&rows[i][ch * 4] = *(const f32x4*)(score + (size_t)mem[i] * DDIM + ch * 4);
    }
    for (int i = tid; i < n; i += 256) rows[i][128] = mag[mem[i]];
    // gather Nfull from the 64 panel partials per member
    for (int w = tid; w < n * 64; w += 256) {
      int i = w >> 6, q = w & 63;
      int gi = mem[i], pp = gi >> 7, off = gi & 127;
      float v = (q >= pp) ? P[(size_t)(q * (q + 1) / 2 + pp) * 256 + off]
                          : P[(size_t)(pp * (pp + 1) / 2 + q) * 256 + 128 + off];
      atomicAdd(&Nf[i], v);
    }
    __syncthreads();
    const int np = n * n;
    for (int p = tid; p < np; p += 256) {
      int i = p / n, j = p - i * n;
      float dd = 0.0f;
      if (i != j) {
        float dot = 0.0f;
        #pragma unroll
        for (int k = 0; k < 32; ++k) {
          f32x4 a = *(const f32x4*)&rows[i][k * 4];
          f32x4 b = *(const f32x4*)&rows[j][k * 4];
          dot += a[0]*b[0] + a[1]*b[1] + a[2]*b[2] + a[3]*b[3];
        }
        float d2 = fmaxf(rows[i][128] + rows[j][128] - 2.0f * dot, 0.0f);
        dd = fast_sqrt(d2);
        atomicAdd(&Ns[i], fast_exp2((1.0f - dd) * L2E));
      }
      dmat[p] = dd;
    }
    __syncthreads();
    for (int i = tid; i < n; i += 256) Nf[i] -= Ns[i];
    __syncthreads();
    float ll = 0.0f, lcn = 0.0f;
    for (int p = tid; p < np; p += 256) {
      int i = p / n, j = p - i * n;
      if (i == j) continue;
      float ln = fast_log2(Nf[i] + Nf[j]) * RLN2 + dmat[p];
      if (ln > 0.0f) ll += ln * ln;
      lcn += 1.0f;
    }
    #pragma unroll
    for (int m = 1; m < 64; m <<= 1) {
      ll  += __shfl_xor(ll, m);
      lcn += __shfl_xor(lcn, m);
    }
    if ((tid & 63) == 0) { redL[tid >> 6] = ll; redC[tid >> 6] = lcn; }
    __syncthreads();
    if (tid == 0) {
      atomicAdd(lossAcc, redL[0] + redL[1] + redL[2] + redL[3]);
      atomicAdd(cntAcc, redC[0] + redC[1] + redC[2] + redC[3]);
    }
  }
  if (tid == 0) {
    __threadfence();
    int done = atomicAdd(ticket, 1);
    if (done == nblocks - 1) {
      float L = atomicAdd(lossAcc, 0.0f);
      float C = atomicAdd(cntAcc, 0.0f);
      out[0] = L / (4.0f * C);
    }
  }
}

extern "C" void kernel_launch(void* const* d_in, const int* in_sizes, int n_in,
                              void* d_out, int out_size, void* d_ws, size_t ws_size,
                              hipStream_t stream) {
  const float* score = (const float*)d_in[0];
  const int* targets = (const int*)d_in[1];
  float* out = (float*)d_out;

  char* ws = (char*)d_ws;
  size_t cur = 0;
  auto alloc = [&](size_t bytes) -> void* {
    void* p = ws + cur;
    cur += (bytes + 255) & ~(size_t)255;
    return p;
  };
  __hip_bfloat16* Sbf = (__hip_bfloat16*)alloc((size_t)BSZ * DDIM * 2);
  float* mag  = (float*)alloc(BSZ * 4);
  int*   ctrl = (int*)alloc(544 * 4);   // counts[512] | loss | cnt | ticket
  int*   list = (int*)alloc(NCLS * SLOT * 4);
  float* P    = (float*)alloc((size_t)NTRI * 256 * 4);

  int*   counts  = ctrl;
  float* lossAcc = (float*)(ctrl + 512);
  float* cntAcc  = (float*)(ctrl + 513);
  int*   ticket  = ctrl + 514;

  hipMemsetAsync(ctrl, 0, 516 * 4, stream);
  prep_kernel<<<BSZ * 16 / 256, 256, 0, stream>>>(score, targets, Sbf, mag,
                                                  counts, list);
  dense_pass<<<NTRI, 256, 0, stream>>>(Sbf, mag, P);
  class_pass<<<NCLS, 256, 0, stream>>>(score, mag, P, counts, list,
                                       lossAcc, cntAcc, ticket, out, NCLS);
}

// Round 5
// 77.861 us; speedup vs baseline: 1.7763x; 1.0044x over previous
//
#include <hip/hip_runtime.h>
#include <hip/hip_bf16.h>

typedef __attribute__((ext_vector_type(8))) short bf16x8;
typedef __attribute__((ext_vector_type(4))) float f32x4;
typedef __attribute__((ext_vector_type(4))) int i32x4;

#define BSZ   8192
#define DDIM  128
#define NCLS  512
#define SLOT  64                    // max members/class supported (actual max ~35)
#define NPAN  64                    // 128-row panels
#define NTRI  (NPAN * (NPAN + 1) / 2)   // 2080 upper-triangular 128x128 tiles

#define L2E  1.44269504088896340736f
#define RLN2 0.69314718055994530942f

__device__ __forceinline__ float fast_sqrt(float x) {
  float r; asm("v_sqrt_f32 %0, %1" : "=v"(r) : "v"(x)); return r;
}
__device__ __forceinline__ float fast_exp2(float x) {
  float r; asm("v_exp_f32 %0, %1" : "=v"(r) : "v"(x)); return r;
}
__device__ __forceinline__ float fast_log2(float x) {
  float r; asm("v_log_f32 %0, %1" : "=v"(r) : "v"(x)); return r;
}

// Zero the 516-word control block (counts[512] | loss | cnt | ticket).
__global__ void zero_kernel(int* __restrict__ ctrl) {
  int t = threadIdx.x;
  ctrl[t] = 0; ctrl[t + 256] = 0;
  if (t < 4) ctrl[t + 512] = 0;
}

// score -> bf16 copy + exact fp32 row magnitudes + class-bucket scatter.
__global__ void prep_kernel(const float* __restrict__ score,
                            const int* __restrict__ targets,
                            __hip_bfloat16* __restrict__ Sbf,
                            float* __restrict__ mag,
                            int* __restrict__ counts,
                            int* __restrict__ list) {
  int gid = blockIdx.x * 256 + threadIdx.x;   // 131072 threads
  int row = gid >> 4, sub = gid & 15;
  const f32x4* src = (const f32x4*)(score + (size_t)row * DDIM + sub * 8);
  f32x4 a = src[0], b = src[1];
  union { ushort u[8]; i32x4 v; } pk;
  #pragma unroll
  for (int k = 0; k < 4; ++k) {
    __hip_bfloat16 ha = __float2bfloat16(a[k]);
    __hip_bfloat16 hb = __float2bfloat16(b[k]);
    pk.u[k] = *(const ushort*)&ha;
    pk.u[4 + k] = *(const ushort*)&hb;
  }
  *(i32x4*)((short*)Sbf + (size_t)row * DDIM + sub * 8) = pk.v;
  float sq = a[0]*a[0] + a[1]*a[1] + a[2]*a[2] + a[3]*a[3]
           + b[0]*b[0] + b[1]*b[1] + b[2]*b[2] + b[3]*b[3];
  sq += __shfl_xor(sq, 1); sq += __shfl_xor(sq, 2);
  sq += __shfl_xor(sq, 4); sq += __shfl_xor(sq, 8);
  if (sub == 0) {
    mag[row] = sq;
    int t = targets[row];
    int p = atomicAdd(&counts[t], 1);
    if (p < SLOT) list[t * SLOT + p] = row;
  }
}

// Dense symmetric pass: one 256-thread block per upper-triangular 128x128
// tile; 2x2 waves of 64x64. A/B staged to LDS via global_load_lds (16B,
// wave-uniform dest) with XOR-swizzle applied on the global SOURCE address
// (rule #21) and the same involution on ds_read -> conflict-free b128 reads.
// Partial row sums (slots 0..127) / col sums (128..255) stored to P[t][.].
__launch_bounds__(256, 2)
__global__ void dense_pass(const __hip_bfloat16* __restrict__ Sbf,
                           const float* __restrict__ mag,
                           float* __restrict__ P) {
  const int t = blockIdx.x;
  int bj = (int)((sqrtf(8.0f * (float)t + 1.0f) - 1.0f) * 0.5f);
  while ((bj + 1) * (bj + 2) / 2 <= t) ++bj;
  while (bj * (bj + 1) / 2 > t) --bj;
  const int bi = t - bj * (bj + 1) / 2;          // bi <= bj
  const int i0 = bi * 128, j0 = bj * 128;
  const bool diag = (bi == bj);

  __shared__ char As[128 * 256];                 // 32 KB, swizzled layout
  __shared__ char Bs[128 * 256];
  __shared__ float Lrow[128][2];
  __shared__ float Lcol[128][2];

  const int tid = threadIdx.x;
  const int wid = tid >> 6, l = tid & 63;
  const int wr = wid >> 1, wc = wid & 1;         // 2x2 wave grid
  const int lr = l >> 4, lc = l & 15;
  const short* S = (const short*)Sbf;

  // Stage: physical chunk p (16B) holds global chunk (p&15)^((p>>4)&7).
  #pragma unroll
  for (int it = 0; it < 8; ++it) {
    int p = tid + it * 256;                      // 2048 chunks per tile
    int r = p >> 4;
    int g = (p & 15) ^ (r & 7);
    const void* gsrcA = (const void*)(S + (size_t)(i0 + r) * DDIM + g * 8);
    void* ldstA = (void*)(As + (wid * 64 + it * 256) * 16);
    __builtin_amdgcn_global_load_lds(
        (const __attribute__((address_space(1))) void*)gsrcA,
        (__attribute__((address_space(3))) void*)ldstA, 16, 0, 0);
    if (!diag) {
      const void* gsrcB = (const void*)(S + (size_t)(j0 + r) * DDIM + g * 8);
      void* ldstB = (void*)(Bs + (wid * 64 + it * 256) * 16);
      __builtin_amdgcn_global_load_lds(
          (const __attribute__((address_space(1))) void*)gsrcB,
          (__attribute__((address_space(3))) void*)ldstB, 16, 0, 0);
    }
  }

  // Prefetch mags while stage is in flight.
  float magj[4], magi[4][4];
  #pragma unroll
  for (int n = 0; n < 4; ++n) magj[n] = mag[j0 + wc * 64 + n * 16 + lc];
  #pragma unroll
  for (int m = 0; m < 4; ++m)
    #pragma unroll
    for (int r = 0; r < 4; ++r)
      magi[m][r] = mag[i0 + wr * 64 + m * 16 + lr * 4 + r];

  __syncthreads();

  const char* BB = diag ? As : Bs;
  f32x4 acc[4][4] = {};
  #pragma unroll
  for (int ks = 0; ks < 4; ++ks) {               // K = 128 in 4 steps of 32
    bf16x8 af[4], bfr[4];
    #pragma unroll
    for (int m = 0; m < 4; ++m) {
      int r = wr * 64 + m * 16 + lc;
      int c = ks * 4 + lr;
      af[m] = *(const bf16x8*)(As + r * 256 + ((c ^ (r & 7)) << 4));
    }
    #pragma unroll
    for (int n = 0; n < 4; ++n) {
      int r = wc * 64 + n * 16 + lc;
      int c = ks * 4 + lr;
      bfr[n] = *(const bf16x8*)(BB + r * 256 + ((c ^ (r & 7)) << 4));
    }
    #pragma unroll
    for (int m = 0; m < 4; ++m)
      #pragma unroll
      for (int n = 0; n < 4; ++n)
        acc[m][n] = __builtin_amdgcn_mfma_f32_16x16x32_bf16(af[m], bfr[n], acc[m][n], 0, 0, 0);
  }

  float rs[4][4] = {};
  float cs[4] = {};
  #pragma unroll
  for (int m = 0; m < 4; ++m)
    #pragma unroll
    for (int n = 0; n < 4; ++n)
      #pragma unroll
      for (int r = 0; r < 4; ++r) {
        // C layout: col = lane&15, row = (lane>>4)*4 + reg
        float d2 = fmaxf(magi[m][r] + magj[n] - 2.0f * acc[m][n][r], 0.0f);
        float e = fast_exp2((1.0f - fast_sqrt(d2)) * L2E);
        rs[m][r] += e;
        cs[n] += e;
      }
  // remove self terms (diag tiles, diag waves only; static indexing)
  if (diag && wr == wc) {
    #pragma unroll
    for (int m = 0; m < 4; ++m)
      #pragma unroll
      for (int r = 0; r < 4; ++r) {
        if (lc == lr * 4 + r) {
          float d2 = fmaxf(magi[m][r] + magj[m] - 2.0f * acc[m][m][r], 0.0f);
          rs[m][r] -= fast_exp2((1.0f - fast_sqrt(d2)) * L2E);
        }
      }
  }

  #pragma unroll
  for (int m = 0; m < 4; ++m)
    #pragma unroll
    for (int r = 0; r < 4; ++r) {
      float v = rs[m][r];
      v += __shfl_xor(v, 1); v += __shfl_xor(v, 2);
      v += __shfl_xor(v, 4); v += __shfl_xor(v, 8);
      if (lc == 0) Lrow[wr * 64 + m * 16 + lr * 4 + r][wc] = v;
    }
  if (!diag) {
    #pragma unroll
    for (int n = 0; n < 4; ++n) {
      float v = cs[n];
      v += __shfl_xor(v, 16); v += __shfl_xor(v, 32);
      if (lr == 0) Lcol[wc * 64 + n * 16 + lc][wr] = v;
    }
  }
  __syncthreads();
  float* Pt = P + (size_t)t * 256;
  if (tid < 128) Pt[tid] = Lrow[tid][0] + Lrow[tid][1];
  else if (!diag) Pt[tid] = Lcol[tid - 128][0] + Lcol[tid - 128][1];
}

// Per-class pass: gather Nfull from tile partials, exact fp32 pairwise
// distances among class members (LDS-staged rows), loss + count; the last
// block to finish finalizes the output (fence + ticket).
__launch_bounds__(256)
__global__ void class_pass(const float* __restrict__ score,
                           const float* __restrict__ mag,
                           const float* __restrict__ P,
                           const int* __restrict__ counts,
                           const int* __restrict__ list,
                           float* lossAcc, float* cntAcc, int* ticket,
                           float* out, int nblocks) {
  const int c = blockIdx.x;
  const int tid = threadIdx.x;
  int n = counts[c];
  if (n > SLOT) n = SLOT;   // defensive; cannot happen for this data
  if (n >= 2) {
    __shared__ float rows[SLOT][132];   // [.][128] holds mag
    __shared__ float Nf[SLOT];
    __shared__ float Ns[SLOT];
    __shared__ int mem[SLOT];
    __shared__ float dmat[SLOT * SLOT];
    __shared__ float redL[4], redC[4];
    for (int i = tid; i < n; i += 256) {
      mem[i] = list[c * SLOT + i];
      Ns[i] = 0.0f; Nf[i] = 0.0f;
    }
    __syncthreads();
    for (int w = tid; w < n * 32; w += 256) {
      int i = w >> 5, ch = w & 31;
      *(f32x4*)&rows[i][ch * 4] = *(const f32x4*)(score + (size_t)mem[i] * DDIM + ch * 4);
    }
    for (int i = tid; i < n; i += 256) rows[i][128] = mag[mem[i]];
    // gather Nfull from the 64 panel partials per member
    for (int w = tid; w < n * 64; w += 256) {
      int i = w >> 6, q = w & 63;
      int gi = mem[i], pp = gi >> 7, off = gi & 127;
      float v = (q >= pp) ? P[(size_t)(q * (q + 1) / 2 + pp) * 256 + off]
                          : P[(size_t)(pp * (pp + 1) / 2 + q) * 256 + 128 + off];
      atomicAdd(&Nf[i], v);
    }
    __syncthreads();
    const int np = n * n;
    for (int p = tid; p < np; p += 256) {
      int i = p / n, j = p - i * n;
      float dd = 0.0f;
      if (i != j) {
        float dot = 0.0f;
        #pragma unroll
        for (int k = 0; k < 32; ++k) {
          f32x4 a = *(const f32x4*)&rows[i][k * 4];
          f32x4 b = *(const f32x4*)&rows[j][k * 4];
          dot += a[0]*b[0] + a[1]*b[1] + a[2]*b[2] + a[3]*b[3];
        }
        float d2 = fmaxf(rows[i][128] + rows[j][128] - 2.0f * dot, 0.0f);
        dd = fast_sqrt(d2);
        atomicAdd(&Ns[i], fast_exp2((1.0f - dd) * L2E));
      }
      dmat[p] = dd;
    }
    __syncthreads();
    for (int i = tid; i < n; i += 256) Nf[i] -= Ns[i];
    __syncthreads();
    float ll = 0.0f, lcn = 0.0f;
    for (int p = tid; p < np; p += 256) {
      int i = p / n, j = p - i * n;
      if (i == j) continue;
      float ln = fast_log2(Nf[i] + Nf[j]) * RLN2 + dmat[p];
      if (ln > 0.0f) ll += ln * ln;
      lcn += 1.0f;
    }
    #pragma unroll
    for (int m = 1; m < 64; m <<= 1) {
      ll  += __shfl_xor(ll, m);
      lcn += __shfl_xor(lcn, m);
    }
    if ((tid & 63) == 0) { redL[tid >> 6] = ll; redC[tid >> 6] = lcn; }
    __syncthreads();
    if (tid == 0) {
      atomicAdd(lossAcc, redL[0] + redL[1] + redL[2] + redL[3]);
      atomicAdd(cntAcc, redC[0] + redC[1] + redC[2] + redC[3]);
    }
  }
  if (tid == 0) {
    __threadfence();
    int done = atomicAdd(ticket, 1);
    if (done == nblocks - 1) {
      float L = atomicAdd(lossAcc, 0.0f);
      float C = atomicAdd(cntAcc, 0.0f);
      out[0] = L / (4.0f * C);
    }
  }
}

extern "C" void kernel_launch(void* const* d_in, const int* in_sizes, int n_in,
                              void* d_out, int out_size, void* d_ws, size_t ws_size,
                              hipStream_t stream) {
  const float* score = (const float*)d_in[0];
  const int* targets = (const int*)d_in[1];
  float* out = (float*)d_out;

  char* ws = (char*)d_ws;
  size_t cur = 0;
  auto alloc = [&](size_t bytes) -> void* {
    void* p = ws + cur;
    cur += (bytes + 255) & ~(size_t)255;
    return p;
  };
  __hip_bfloat16* Sbf = (__hip_bfloat16*)alloc((size_t)BSZ * DDIM * 2);
  float* mag  = (float*)alloc(BSZ * 4);
  int*   ctrl = (int*)alloc(544 * 4);   // counts[512] | loss | cnt | ticket
  int*   list = (int*)alloc(NCLS * SLOT * 4);
  float* P    = (float*)alloc((size_t)NTRI * 256 * 4);

  int*   counts  = ctrl;
  float* lossAcc = (float*)(ctrl + 512);
  float* cntAcc  = (float*)(ctrl + 513);
  int*   ticket  = ctrl + 514;

  zero_kernel<<<1, 256, 0, stream>>>(ctrl);
  prep_kernel<<<BSZ * 16 / 256, 256, 0, stream>>>(score, targets, Sbf, mag,
                                                  counts, list);
  dense_pass<<<NTRI, 256, 0, stream>>>(Sbf, mag, P);
  class_pass<<<NCLS, 256, 0, stream>>>(score, mag, P, counts, list,
                                       lossAcc, cntAcc, ticket, out, NCLS);
}